// Round 1
// baseline (371490.552 us; speedup 1.0000x reference)
//
#include <hip/hip_runtime.h>

#define T_LEN  12800
#define BATCH  4
#define HID    512
#define NFEAT  80
#define FRAMES 54
#define CCH    128
#define LRES   50
#define M_ROWS (BATCH * T_LEN)   // 51200

// ---------------------------------------------------------------------------
// mel resnet: conv_in (K=5, VALID) + bn0 + relu
// ---------------------------------------------------------------------------
__global__ __launch_bounds__(128)
void k_conv_in(const float* __restrict__ mels, const float* __restrict__ w,
               const float* __restrict__ g, const float* __restrict__ bb,
               float* __restrict__ out) {
    int blk = blockIdx.x;            // b*LRES + l
    int b = blk / LRES, l = blk % LRES;
    int o = threadIdx.x;
    __shared__ float ms[NFEAT * 5];
    for (int i = o; i < NFEAT * 5; i += 128) {
        int c = i / 5, k = i % 5;
        ms[i] = mels[(b * NFEAT + c) * FRAMES + l + k];
    }
    __syncthreads();
    const float* wr = w + o * NFEAT * 5;
    float s = 0.f;
    for (int i = 0; i < NFEAT * 5; ++i) s = fmaf(ms[i], wr[i], s);
    float inv = g[o] * rsqrtf(1.f + 1e-5f);
    s = s * inv + bb[o];
    out[(b * CCH + o) * LRES + l] = fmaxf(s, 0.f);
}

// einsum 'bcl,oc->bol' (+bn variants). MODE 0: bn+relu; 1: bn + residual; 2: +bias
template <int MODE>
__global__ __launch_bounds__(128)
void k_ein(const float* __restrict__ x, const float* __restrict__ w,
           const float* __restrict__ g, const float* __restrict__ bb,
           const float* __restrict__ res, float* __restrict__ out) {
    int blk = blockIdx.x;
    int b = blk / LRES, l = blk % LRES;
    int o = threadIdx.x;
    __shared__ float xs[CCH];
    xs[o] = x[(b * CCH + o) * LRES + l];
    __syncthreads();
    const float* wr = w + o * CCH;
    float s = 0.f;
#pragma unroll 8
    for (int c = 0; c < CCH; ++c) s = fmaf(xs[c], wr[c], s);
    float v;
    if (MODE == 2) {
        v = s + bb[o];
    } else {
        float inv = g[o] * rsqrtf(1.f + 1e-5f);
        v = s * inv + bb[o];
        if (MODE == 0) v = fmaxf(v, 0.f);
        else           v = v + res[(b * CCH + o) * LRES + l];
    }
    out[(b * CCH + o) * LRES + l] = v;
}

// aux repeat: aux_t[b][t][ch] = aux_small[b][ch][t>>8]
__global__ __launch_bounds__(256)
void k_auxrep(const float* __restrict__ aux_s, float* __restrict__ aux_t) {
    int idx = blockIdx.x * 256 + threadIdx.x;   // < B*T*128 (exact)
    int ch = idx & 127;
    int bt = idx >> 7;
    int t = bt % T_LEN, b = bt / T_LEN;
    aux_t[idx] = aux_s[(b * CCH + ch) * LRES + (t >> 8)];
}

// ---------------------------------------------------------------------------
// upsample: 3 repeat+conv stages
// ---------------------------------------------------------------------------
__global__ __launch_bounds__(256)
void k_up1(const float* __restrict__ mels, const float* __restrict__ w0, float* __restrict__ s1) {
    int idx = blockIdx.x * 256 + threadIdx.x;  // B*80*216 exact
    int i = idx % 216; int bc = idx / 216;
    float s = 0.f;
#pragma unroll
    for (int k = 0; k < 9; ++k) {
        int q = i + k - 4;
        if (q >= 0 && q < 216) s = fmaf(w0[k], mels[bc * FRAMES + (q >> 2)], s);
    }
    s1[idx] = s;
}
__global__ __launch_bounds__(256)
void k_up2(const float* __restrict__ s1, const float* __restrict__ w1, float* __restrict__ s2) {
    int idx = blockIdx.x * 256 + threadIdx.x;  // B*80*1728 exact
    int j = idx % 1728; int bc = idx / 1728;
    float s = 0.f;
#pragma unroll
    for (int k = 0; k < 17; ++k) {
        int q = j + k - 8;
        if (q >= 0 && q < 1728) s = fmaf(w1[k], s1[bc * 216 + (q >> 3)], s);
    }
    s2[idx] = s;
}
__global__ __launch_bounds__(256)
void k_up3(const float* __restrict__ s2, const float* __restrict__ w2, float* __restrict__ mup) {
    int idx = blockIdx.x * 256 + threadIdx.x;  // B*T*80 exact
    int c = idx % NFEAT; int bt = idx / NFEAT;
    int t = bt % T_LEN; int b = bt / T_LEN;
    const float* src = s2 + (b * NFEAT + c) * 1728;
    float s = 0.f;
#pragma unroll
    for (int k = 0; k < 17; ++k) s = fmaf(w2[k], src[(t + 504 + k) >> 3], s);
    mup[idx] = s;
}

// ---------------------------------------------------------------------------
// fp32 GEMM: C[M,N] = act( concat(A1,A2,A3) @ W[N,K]^T + bias )
// tile 128x128, BK=8, 256 threads, 8x8 per thread. Grid: (N/128, M/128).
// ---------------------------------------------------------------------------
template <int ACT>
__global__ __launch_bounds__(256)
void gemm_f32(const float* __restrict__ A1, int lda1, int K1,
              const float* __restrict__ A2, int lda2, int K2,
              const float* __restrict__ A3, int lda3, int K3,
              const float* __restrict__ W, const float* __restrict__ bias,
              float* __restrict__ C, int N, int K) {
    __shared__ float As[8][128];
    __shared__ float Bs[8][128];
    int tid = threadIdx.x;
    int n0 = blockIdx.x * 128, m0 = blockIdx.y * 128;
    int tx = tid & 15, ty = tid >> 4;
    int row = tid >> 1;
    int kc = (tid & 1) * 4;
    float acc[8][8];
#pragma unroll
    for (int r = 0; r < 8; ++r)
#pragma unroll
        for (int c = 0; c < 8; ++c) acc[r][c] = 0.f;

    for (int k0 = 0; k0 < K; k0 += 8) {
#pragma unroll
        for (int e = 0; e < 4; ++e) {
            int gk = k0 + kc + e;
            int m = m0 + row;
            float v = 0.f;
            if (gk < K1)            v = A1[(size_t)m * lda1 + gk];
            else if (gk < K1 + K2)  v = A2[(size_t)m * lda2 + (gk - K1)];
            else if (gk < K)        v = A3[(size_t)m * lda3 + (gk - K1 - K2)];
            As[kc + e][row] = v;
            float wv = (gk < K) ? W[(size_t)(n0 + row) * K + gk] : 0.f;
            Bs[kc + e][row] = wv;
        }
        __syncthreads();
#pragma unroll
        for (int kk = 0; kk < 8; ++kk) {
            float a[8], bv[8];
#pragma unroll
            for (int h = 0; h < 2; ++h) {
                float4 t4 = *(const float4*)&As[kk][ty * 8 + h * 4];
                a[h * 4 + 0] = t4.x; a[h * 4 + 1] = t4.y; a[h * 4 + 2] = t4.z; a[h * 4 + 3] = t4.w;
                float4 u4 = *(const float4*)&Bs[kk][tx * 8 + h * 4];
                bv[h * 4 + 0] = u4.x; bv[h * 4 + 1] = u4.y; bv[h * 4 + 2] = u4.z; bv[h * 4 + 3] = u4.w;
            }
#pragma unroll
            for (int r = 0; r < 8; ++r)
#pragma unroll
                for (int c = 0; c < 8; ++c) acc[r][c] = fmaf(a[r], bv[c], acc[r][c]);
        }
        __syncthreads();
    }
#pragma unroll
    for (int r = 0; r < 8; ++r) {
        int m = m0 + ty * 8 + r;
        float* co = C + (size_t)m * N + n0 + tx * 8;
#pragma unroll
        for (int c = 0; c < 8; ++c) {
            float v = acc[r][c] + bias[n0 + tx * 8 + c];
            if (ACT) v = fmaxf(v, 0.f);
            co[c] = v;
        }
    }
}

// ---------------------------------------------------------------------------
// Persistent GRU recurrence. 4 clusters (one per batch) x 16 WGs x 384 thr.
// Each thread holds 4 rows x 32 k of whh in 128 VGPRs. h broadcast via
// agent-scope atomics through a 2-slot global buffer + per-WG flags.
// ---------------------------------------------------------------------------
#define SWZ(i) ((i) + (((i) >> 5) << 2))

__global__ __launch_bounds__(384)
void k_gru(const float* __restrict__ xp, const float* __restrict__ whh,
           const float* __restrict__ bhh, const float* __restrict__ skip,
           float* __restrict__ hseq, float* hbuf, int* flags) {
    int blk = blockIdx.x;
    int cb = blk & 7;               // cluster (=batch); one XCD under round-robin
    if (cb >= BATCH) return;
    int wg = blk >> 3;              // 0..15
    int tid = threadIdx.x;
    int ch0 = wg * 32;
    int rg = tid >> 4;              // 0..23 (4 rows each)
    int p = tid & 15;               // 32-wide k chunk

    float* hb = hbuf + cb * 2 * HID;
    int* flg = flags + cb * 16;

    // resident weights: rows lr = rg*4+j -> R = (lr>>5)*512 + ch0 + (lr&31)
    float w[128];
#pragma unroll
    for (int j = 0; j < 4; ++j) {
        int lr = rg * 4 + j;
        int R = (lr >> 5) * HID + ch0 + (lr & 31);
        const float* src = whh + (size_t)R * HID + p * 32;
#pragma unroll
        for (int q = 0; q < 8; ++q) {
            float4 v = *(const float4*)&src[q * 4];
            w[j * 32 + q * 4 + 0] = v.x; w[j * 32 + q * 4 + 1] = v.y;
            w[j * 32 + q * 4 + 2] = v.z; w[j * 32 + q * 4 + 3] = v.w;
        }
    }
    float bR = 0.f, bZ = 0.f, bN = 0.f;
    if (tid < 32) {
        bR = bhh[ch0 + tid];
        bZ = bhh[HID + ch0 + tid];
        bN = bhh[2 * HID + ch0 + tid];
    }

    __shared__ float h_lds[576];
    __shared__ float gh_lds[96];
    const size_t brow = (size_t)cb * T_LEN;
    int spin_budget = 1 << 22;      // global anti-hang budget

    for (int t = 0; t < T_LEN; ++t) {
        // prefetch step inputs (no dependence on h)
        float xr = 0.f, xz = 0.f, xn = 0.f, skv = 0.f;
        if (tid < 32) {
            const float* xpt = xp + (brow + t) * 1536;
            xr = xpt[ch0 + tid];
            xz = xpt[HID + ch0 + tid];
            xn = xpt[2 * HID + ch0 + tid];
            skv = skip[(brow + t) * HID + ch0 + tid];
        }
        if (t == 0) {
            { int i = tid; h_lds[SWZ(i)] = 0.f; }
            if (tid < 128) { int i = 384 + tid; h_lds[SWZ(i)] = 0.f; }
        } else {
            if (tid < 64) {
                while (true) {
                    int v = (tid < 16)
                        ? __hip_atomic_load(&flg[tid], __ATOMIC_RELAXED, __HIP_MEMORY_SCOPE_AGENT)
                        : t;
                    if (__all(v >= t)) break;
                    if (--spin_budget < 0) break;
                }
            }
            __syncthreads();
            __threadfence();   // acquire: published h slices now visible
            const float* hc = hb + (t & 1) * HID;
            { int i = tid;
              float v = __hip_atomic_load(&hc[i], __ATOMIC_RELAXED, __HIP_MEMORY_SCOPE_AGENT);
              h_lds[SWZ(i)] = v; }
            if (tid < 128) { int i = 384 + tid;
              float v = __hip_atomic_load(&hc[i], __ATOMIC_RELAXED, __HIP_MEMORY_SCOPE_AGENT);
              h_lds[SWZ(i)] = v; }
        }
        __syncthreads();

        // dot: 4 rows x (32-wide chunk)
        float hreg[32];
        int hbase = p * 36;   // swizzled chunk base (16B aligned)
#pragma unroll
        for (int q = 0; q < 8; ++q) {
            float4 v = *(const float4*)&h_lds[hbase + q * 4];
            hreg[q * 4 + 0] = v.x; hreg[q * 4 + 1] = v.y;
            hreg[q * 4 + 2] = v.z; hreg[q * 4 + 3] = v.w;
        }
        float a0 = 0.f, a1 = 0.f, a2 = 0.f, a3 = 0.f;
#pragma unroll
        for (int i = 0; i < 32; ++i) {
            float hv = hreg[i];
            a0 = fmaf(w[i], hv, a0);
            a1 = fmaf(w[32 + i], hv, a1);
            a2 = fmaf(w[64 + i], hv, a2);
            a3 = fmaf(w[96 + i], hv, a3);
        }
        a0 += __shfl_xor(a0, 1); a0 += __shfl_xor(a0, 2); a0 += __shfl_xor(a0, 4); a0 += __shfl_xor(a0, 8);
        a1 += __shfl_xor(a1, 1); a1 += __shfl_xor(a1, 2); a1 += __shfl_xor(a1, 4); a1 += __shfl_xor(a1, 8);
        a2 += __shfl_xor(a2, 1); a2 += __shfl_xor(a2, 2); a2 += __shfl_xor(a2, 4); a2 += __shfl_xor(a2, 8);
        a3 += __shfl_xor(a3, 1); a3 += __shfl_xor(a3, 2); a3 += __shfl_xor(a3, 4); a3 += __shfl_xor(a3, 8);
        if (p == 0) {
            gh_lds[rg * 4 + 0] = a0;
            gh_lds[rg * 4 + 1] = a1;
            gh_lds[rg * 4 + 2] = a2;
            gh_lds[rg * 4 + 3] = a3;
        }
        __syncthreads();

        if (tid < 32) {
            float hr = gh_lds[tid], hz = gh_lds[32 + tid], hn = gh_lds[64 + tid];
            float rr = 1.f / (1.f + __expf(-(xr + hr + bR)));
            float zz = 1.f / (1.f + __expf(-(xz + hz + bZ)));
            float nn = tanhf(xn + rr * (hn + bN));
            int i = ch0 + tid;
            float hp = h_lds[SWZ(i)];
            float hnew = (1.f - zz) * nn + zz * hp;
            float* hnx = hb + ((t + 1) & 1) * HID;
            __hip_atomic_store(&hnx[i], hnew, __ATOMIC_RELAXED, __HIP_MEMORY_SCOPE_AGENT);
            hseq[(brow + t) * HID + i] = hnew + skv;
        }
        if (tid == 0) {
            __threadfence();   // release: h slice visible before flag
            __hip_atomic_store(&flg[wg], t + 1, __ATOMIC_RELAXED, __HIP_MEMORY_SCOPE_AGENT);
        }
        // no trailing barrier needed: next-step stage is gated by the post-spin
        // barrier, which wave0 reaches only after its combine.
    }
}

// ---------------------------------------------------------------------------
extern "C" void kernel_launch(void* const* d_in, const int* in_sizes, int n_in,
                              void* d_out, int out_size, void* d_ws, size_t ws_size,
                              hipStream_t stream) {
    (void)in_sizes; (void)n_in; (void)out_size; (void)ws_size;
    const float* x         = (const float*)d_in[0];
    const float* mels      = (const float*)d_in[1];
    const float* conv_in_w = (const float*)d_in[2];
    const float* bn0_g     = (const float*)d_in[3];
    const float* bn0_b     = (const float*)d_in[4];
    const float* res_c1    = (const float*)d_in[5];
    const float* res_c2    = (const float*)d_in[6];
    const float* res_bn1_g = (const float*)d_in[7];
    const float* res_bn1_b = (const float*)d_in[8];
    const float* res_bn2_g = (const float*)d_in[9];
    const float* res_bn2_b = (const float*)d_in[10];
    const float* conv_out_w= (const float*)d_in[11];
    const float* conv_out_b= (const float*)d_in[12];
    const float* up_w0     = (const float*)d_in[13];
    const float* up_w1     = (const float*)d_in[14];
    const float* up_w2     = (const float*)d_in[15];
    const float* I_w       = (const float*)d_in[16];
    const float* I_b       = (const float*)d_in[17];
    const float* r1_wih    = (const float*)d_in[18];
    const float* r1_whh    = (const float*)d_in[19];
    const float* r1_bih    = (const float*)d_in[20];
    const float* r1_bhh    = (const float*)d_in[21];
    const float* r2_wih    = (const float*)d_in[22];
    const float* r2_whh    = (const float*)d_in[23];
    const float* r2_bih    = (const float*)d_in[24];
    const float* r2_bhh    = (const float*)d_in[25];
    const float* fc1_w     = (const float*)d_in[26];
    const float* fc1_b     = (const float*)d_in[27];
    const float* fc2_w     = (const float*)d_in[28];
    const float* fc2_b     = (const float*)d_in[29];
    const float* fc3_w     = (const float*)d_in[30];
    const float* fc3_b     = (const float*)d_in[31];

    char* ws = (char*)d_ws;
    size_t off = 0;
    auto alloc = [&](size_t bytes) {
        char* p = ws + off;
        off += (bytes + 255) & ~(size_t)255;
        return p;
    };
    int*   flags1 = (int*)  alloc(256);
    int*   flags2 = (int*)  alloc(256);
    float* hbuf1  = (float*)alloc(4 * 2 * HID * 4);
    float* hbuf2  = (float*)alloc(4 * 2 * HID * 4);
    float* rnA    = (float*)alloc((size_t)BATCH * CCH * LRES * 4);
    float* rnB    = (float*)alloc((size_t)BATCH * CCH * LRES * 4);
    float* aux_s  = (float*)alloc((size_t)BATCH * CCH * LRES * 4);
    float* s1     = (float*)alloc((size_t)BATCH * NFEAT * 216 * 4);
    float* s2     = (float*)alloc((size_t)BATCH * NFEAT * 1728 * 4);
    float* mup    = (float*)alloc((size_t)BATCH * T_LEN * NFEAT * 4);
    float* auxt   = (float*)alloc((size_t)BATCH * T_LEN * CCH * 4);
    float* h0     = (float*)alloc((size_t)M_ROWS * HID * 4);
    float* xp     = (float*)alloc((size_t)M_ROWS * 1536 * 4);
    float* h1     = (float*)alloc((size_t)M_ROWS * HID * 4);
    float* h2     = (float*)alloc((size_t)M_ROWS * HID * 4);
    float* f1 = h0;   // h0 dead after GRU1
    float* f2 = h1;   // h1 dead after GRU2

    hipMemsetAsync(flags1, 0, 512, stream);   // flags1+flags2 contiguous

    // mel resnet
    k_conv_in<<<BATCH * LRES, 128, 0, stream>>>(mels, conv_in_w, bn0_g, bn0_b, rnA);
    for (int i = 0; i < 10; ++i) {
        k_ein<0><<<BATCH * LRES, 128, 0, stream>>>(rnA, res_c1 + (size_t)i * CCH * CCH,
            res_bn1_g + i * CCH, res_bn1_b + i * CCH, nullptr, rnB);
        k_ein<1><<<BATCH * LRES, 128, 0, stream>>>(rnB, res_c2 + (size_t)i * CCH * CCH,
            res_bn2_g + i * CCH, res_bn2_b + i * CCH, rnA, rnA);
    }
    k_ein<2><<<BATCH * LRES, 128, 0, stream>>>(rnA, conv_out_w, nullptr, conv_out_b, nullptr, aux_s);
    k_auxrep<<<(BATCH * T_LEN * CCH) / 256, 256, 0, stream>>>(aux_s, auxt);

    // upsample
    k_up1<<<(BATCH * NFEAT * 216) / 256, 256, 0, stream>>>(mels, up_w0, s1);
    k_up2<<<(BATCH * NFEAT * 1728) / 256, 256, 0, stream>>>(s1, up_w1, s2);
    k_up3<<<(BATCH * T_LEN * NFEAT) / 256, 256, 0, stream>>>(s2, up_w2, mup);

    // h0 = concat(x, m_up, a1) @ I_w^T + I_b
    gemm_f32<0><<<dim3(512 / 128, M_ROWS / 128), 256, 0, stream>>>(
        x, 1, 1, mup, NFEAT, NFEAT, auxt, CCH, 32, I_w, I_b, h0, 512, 113);
    // xp1 = h0 @ r1_wih^T + r1_bih
    gemm_f32<0><<<dim3(1536 / 128, M_ROWS / 128), 256, 0, stream>>>(
        h0, HID, HID, nullptr, 0, 0, nullptr, 0, 0, r1_wih, r1_bih, xp, 1536, 512);
    // GRU1 (writes h1 = gru + h0)
    k_gru<<<128, 384, 0, stream>>>(xp, r1_whh, r1_bhh, h0, h1, hbuf1, flags1);
    // xp2 = concat(h1, a2) @ r2_wih^T + r2_bih
    gemm_f32<0><<<dim3(1536 / 128, M_ROWS / 128), 256, 0, stream>>>(
        h1, HID, HID, auxt + 32, CCH, 32, nullptr, 0, 0, r2_wih, r2_bih, xp, 1536, 544);
    // GRU2 (writes h2 = gru + h1)
    k_gru<<<128, 384, 0, stream>>>(xp, r2_whh, r2_bhh, h1, h2, hbuf2, flags2);
    // fc chain
    gemm_f32<1><<<dim3(512 / 128, M_ROWS / 128), 256, 0, stream>>>(
        h2, HID, HID, auxt + 64, CCH, 32, nullptr, 0, 0, fc1_w, fc1_b, f1, 512, 544);
    gemm_f32<1><<<dim3(512 / 128, M_ROWS / 128), 256, 0, stream>>>(
        f1, HID, HID, auxt + 96, CCH, 32, nullptr, 0, 0, fc2_w, fc2_b, f2, 512, 544);
    gemm_f32<0><<<dim3(1024 / 128, M_ROWS / 128), 256, 0, stream>>>(
        f2, HID, HID, nullptr, 0, 0, nullptr, 0, 0, fc3_w, fc3_b, (float*)d_out, 1024, 512);
}

// Round 3
// 192174.280 us; speedup vs baseline: 1.9331x; 1.9331x over previous
//
#include <hip/hip_runtime.h>

#define T_LEN  12800
#define BATCH  4
#define HID    512
#define NFEAT  80
#define FRAMES 54
#define CCH    128
#define LRES   50
#define M_ROWS (BATCH * T_LEN)   // 51200

#define SCOPE_SYS __HIP_MEMORY_SCOPE_SYSTEM

// ---------------------------------------------------------------------------
// mel resnet: conv_in (K=5, VALID) + bn0 + relu
// ---------------------------------------------------------------------------
__global__ __launch_bounds__(128)
void k_conv_in(const float* __restrict__ mels, const float* __restrict__ w,
               const float* __restrict__ g, const float* __restrict__ bb,
               float* __restrict__ out) {
    int blk = blockIdx.x;            // b*LRES + l
    int b = blk / LRES, l = blk % LRES;
    int o = threadIdx.x;
    __shared__ float ms[NFEAT * 5];
    for (int i = o; i < NFEAT * 5; i += 128) {
        int c = i / 5, k = i % 5;
        ms[i] = mels[(b * NFEAT + c) * FRAMES + l + k];
    }
    __syncthreads();
    const float* wr = w + o * NFEAT * 5;
    float s = 0.f;
    for (int i = 0; i < NFEAT * 5; ++i) s = fmaf(ms[i], wr[i], s);
    float inv = g[o] * rsqrtf(1.f + 1e-5f);
    s = s * inv + bb[o];
    out[(b * CCH + o) * LRES + l] = fmaxf(s, 0.f);
}

// einsum 'bcl,oc->bol' (+bn variants). MODE 0: bn+relu; 1: bn + residual; 2: +bias
template <int MODE>
__global__ __launch_bounds__(128)
void k_ein(const float* __restrict__ x, const float* __restrict__ w,
           const float* __restrict__ g, const float* __restrict__ bb,
           const float* __restrict__ res, float* __restrict__ out) {
    int blk = blockIdx.x;
    int b = blk / LRES, l = blk % LRES;
    int o = threadIdx.x;
    __shared__ float xs[CCH];
    xs[o] = x[(b * CCH + o) * LRES + l];
    __syncthreads();
    const float* wr = w + o * CCH;
    float s = 0.f;
#pragma unroll 8
    for (int c = 0; c < CCH; ++c) s = fmaf(xs[c], wr[c], s);
    float v;
    if (MODE == 2) {
        v = s + bb[o];
    } else {
        float inv = g[o] * rsqrtf(1.f + 1e-5f);
        v = s * inv + bb[o];
        if (MODE == 0) v = fmaxf(v, 0.f);
        else           v = v + res[(b * CCH + o) * LRES + l];
    }
    out[(b * CCH + o) * LRES + l] = v;
}

// aux repeat: aux_t[b][t][ch] = aux_small[b][ch][t>>8]
__global__ __launch_bounds__(256)
void k_auxrep(const float* __restrict__ aux_s, float* __restrict__ aux_t) {
    int idx = blockIdx.x * 256 + threadIdx.x;   // < B*T*128 (exact)
    int ch = idx & 127;
    int bt = idx >> 7;
    int t = bt % T_LEN, b = bt / T_LEN;
    aux_t[idx] = aux_s[(b * CCH + ch) * LRES + (t >> 8)];
}

// ---------------------------------------------------------------------------
// upsample: 3 repeat+conv stages
// ---------------------------------------------------------------------------
__global__ __launch_bounds__(256)
void k_up1(const float* __restrict__ mels, const float* __restrict__ w0, float* __restrict__ s1) {
    int idx = blockIdx.x * 256 + threadIdx.x;  // B*80*216 exact
    int i = idx % 216; int bc = idx / 216;
    float s = 0.f;
#pragma unroll
    for (int k = 0; k < 9; ++k) {
        int q = i + k - 4;
        if (q >= 0 && q < 216) s = fmaf(w0[k], mels[bc * FRAMES + (q >> 2)], s);
    }
    s1[idx] = s;
}
__global__ __launch_bounds__(256)
void k_up2(const float* __restrict__ s1, const float* __restrict__ w1, float* __restrict__ s2) {
    int idx = blockIdx.x * 256 + threadIdx.x;  // B*80*1728 exact
    int j = idx % 1728; int bc = idx / 1728;
    float s = 0.f;
#pragma unroll
    for (int k = 0; k < 17; ++k) {
        int q = j + k - 8;
        if (q >= 0 && q < 1728) s = fmaf(w1[k], s1[bc * 216 + (q >> 3)], s);
    }
    s2[idx] = s;
}
__global__ __launch_bounds__(256)
void k_up3(const float* __restrict__ s2, const float* __restrict__ w2, float* __restrict__ mup) {
    int idx = blockIdx.x * 256 + threadIdx.x;  // B*T*80 exact
    int c = idx % NFEAT; int bt = idx / NFEAT;
    int t = bt % T_LEN; int b = bt / T_LEN;
    const float* src = s2 + (b * NFEAT + c) * 1728;
    float s = 0.f;
#pragma unroll
    for (int k = 0; k < 17; ++k) s = fmaf(w2[k], src[(t + 504 + k) >> 3], s);
    mup[idx] = s;
}

// ---------------------------------------------------------------------------
// fp32 GEMM: C[M,N] = act( concat(A1,A2,A3) @ W[N,K]^T + bias )
// tile 128x128, BK=8, 256 threads, 8x8 per thread. Grid: (N/128, M/128).
// ---------------------------------------------------------------------------
template <int ACT>
__global__ __launch_bounds__(256)
void gemm_f32(const float* __restrict__ A1, int lda1, int K1,
              const float* __restrict__ A2, int lda2, int K2,
              const float* __restrict__ A3, int lda3, int K3,
              const float* __restrict__ W, const float* __restrict__ bias,
              float* __restrict__ C, int N, int K) {
    __shared__ float As[8][128];
    __shared__ float Bs[8][128];
    int tid = threadIdx.x;
    int n0 = blockIdx.x * 128, m0 = blockIdx.y * 128;
    int tx = tid & 15, ty = tid >> 4;
    int row = tid >> 1;
    int kc = (tid & 1) * 4;
    float acc[8][8];
#pragma unroll
    for (int r = 0; r < 8; ++r)
#pragma unroll
        for (int c = 0; c < 8; ++c) acc[r][c] = 0.f;

    for (int k0 = 0; k0 < K; k0 += 8) {
#pragma unroll
        for (int e = 0; e < 4; ++e) {
            int gk = k0 + kc + e;
            int m = m0 + row;
            float v = 0.f;
            if (gk < K1)            v = A1[(size_t)m * lda1 + gk];
            else if (gk < K1 + K2)  v = A2[(size_t)m * lda2 + (gk - K1)];
            else if (gk < K)        v = A3[(size_t)m * lda3 + (gk - K1 - K2)];
            As[kc + e][row] = v;
            float wv = (gk < K) ? W[(size_t)(n0 + row) * K + gk] : 0.f;
            Bs[kc + e][row] = wv;
        }
        __syncthreads();
#pragma unroll
        for (int kk = 0; kk < 8; ++kk) {
            float a[8], bv[8];
#pragma unroll
            for (int h = 0; h < 2; ++h) {
                float4 t4 = *(const float4*)&As[kk][ty * 8 + h * 4];
                a[h * 4 + 0] = t4.x; a[h * 4 + 1] = t4.y; a[h * 4 + 2] = t4.z; a[h * 4 + 3] = t4.w;
                float4 u4 = *(const float4*)&Bs[kk][tx * 8 + h * 4];
                bv[h * 4 + 0] = u4.x; bv[h * 4 + 1] = u4.y; bv[h * 4 + 2] = u4.z; bv[h * 4 + 3] = u4.w;
            }
#pragma unroll
            for (int r = 0; r < 8; ++r)
#pragma unroll
                for (int c = 0; c < 8; ++c) acc[r][c] = fmaf(a[r], bv[c], acc[r][c]);
        }
        __syncthreads();
    }
#pragma unroll
    for (int r = 0; r < 8; ++r) {
        int m = m0 + ty * 8 + r;
        float* co = C + (size_t)m * N + n0 + tx * 8;
#pragma unroll
        for (int c = 0; c < 8; ++c) {
            float v = acc[r][c] + bias[n0 + tx * 8 + c];
            if (ACT) v = fmaxf(v, 0.f);
            co[c] = v;
        }
    }
}

// ---------------------------------------------------------------------------
// Persistent GRU recurrence. 4 clusters (one per batch, one XCD each under
// round-robin dispatch) x 16 WGs x 384 thr. Each thread holds 128 whh floats
// in registers. No __threadfence: all cross-WG traffic uses system-scope
// relaxed atomics (global_load/store sc0 sc1 -> coherent point), release
// ordering via s_waitcnt vmcnt(0), acquire via poll control-dep +
// sched_barrier. Exactly ONE __syncthreads per step (double-buffered gh_lds).
// ---------------------------------------------------------------------------
__global__ __launch_bounds__(384)
void k_gru(const float* __restrict__ xp, const float* __restrict__ whh,
           const float* __restrict__ bhh, const float* __restrict__ skip,
           float* __restrict__ hseq, float* hbuf, int* flags) {
    int blk = blockIdx.x;
    int cb = blk & 7;               // cluster (=batch); one XCD under round-robin
    if (cb >= BATCH) return;
    int wg = blk >> 3;              // 0..15
    int tid = threadIdx.x;
    int lane = tid & 63;
    int ch0 = wg * 32;
    int rg = tid >> 4;              // 0..23 (4 gate-rows each)
    int p = tid & 15;               // 32-wide k chunk

    float* hb = hbuf + cb * 2 * HID;
    int* flg = flags + cb * 16;

    // resident weights: rows lr = rg*4+j -> R = (lr>>5)*512 + ch0 + (lr&31)
    float w[128];
#pragma unroll
    for (int j = 0; j < 4; ++j) {
        int lr = rg * 4 + j;
        int R = (lr >> 5) * HID + ch0 + (lr & 31);
        const float* src = whh + (size_t)R * HID + p * 32;
#pragma unroll
        for (int q = 0; q < 8; ++q) {
            float4 v = *(const float4*)&src[q * 4];
            w[j * 32 + q * 4 + 0] = v.x; w[j * 32 + q * 4 + 1] = v.y;
            w[j * 32 + q * 4 + 2] = v.z; w[j * 32 + q * 4 + 3] = v.w;
        }
    }
    float bR = 0.f, bZ = 0.f, bN = 0.f;
    if (tid < 32) {
        bR = bhh[ch0 + tid];
        bZ = bhh[HID + ch0 + tid];
        bN = bhh[2 * HID + ch0 + tid];
    }

    __shared__ float gh_lds[2][96];
    const size_t brow = (size_t)cb * T_LEN;
    int spin_budget = 1 << 22;      // lifetime anti-hang budget

    for (int t = 0; t < T_LEN; ++t) {
        // prefetch step inputs (no dependence on h) — normal cached loads
        float xr = 0.f, xz = 0.f, xn = 0.f, skv = 0.f;
        if (tid < 32) {
            const float* xpt = xp + (brow + t) * 1536;
            xr = xpt[ch0 + tid];
            xz = xpt[HID + ch0 + tid];
            xn = xpt[2 * HID + ch0 + tid];
            skv = skip[(brow + t) * HID + ch0 + tid];
        }

        float hreg[32];
        float hprev = 0.f;
        if (t > 0) {
            // per-wave poll: all 16 flags of this cluster must reach t
            while (true) {
                int v = (lane < 16)
                    ? __hip_atomic_load(&flg[lane], __ATOMIC_RELAXED, SCOPE_SYS)
                    : t;
                if (__all(v >= t)) break;
                if (--spin_budget < 0) break;
            }
            __builtin_amdgcn_sched_barrier(0);   // keep h loads after the poll
            const float* hc = hb + (t & 1) * HID;
            const float* hpp = hc + p * 32;
#pragma unroll
            for (int i = 0; i < 32; ++i)
                hreg[i] = __hip_atomic_load(&hpp[i], __ATOMIC_RELAXED, SCOPE_SYS);
            if (tid < 32)
                hprev = __hip_atomic_load(&hc[ch0 + tid], __ATOMIC_RELAXED, SCOPE_SYS);
        } else {
#pragma unroll
            for (int i = 0; i < 32; ++i) hreg[i] = 0.f;
        }

        // dot: 4 gate-rows x 32-wide chunk
        float a0 = 0.f, a1 = 0.f, a2 = 0.f, a3 = 0.f;
#pragma unroll
        for (int i = 0; i < 32; ++i) {
            float hv = hreg[i];
            a0 = fmaf(w[i], hv, a0);
            a1 = fmaf(w[32 + i], hv, a1);
            a2 = fmaf(w[64 + i], hv, a2);
            a3 = fmaf(w[96 + i], hv, a3);
        }
        a0 += __shfl_xor(a0, 1); a0 += __shfl_xor(a0, 2); a0 += __shfl_xor(a0, 4); a0 += __shfl_xor(a0, 8);
        a1 += __shfl_xor(a1, 1); a1 += __shfl_xor(a1, 2); a1 += __shfl_xor(a1, 4); a1 += __shfl_xor(a1, 8);
        a2 += __shfl_xor(a2, 1); a2 += __shfl_xor(a2, 2); a2 += __shfl_xor(a2, 4); a2 += __shfl_xor(a2, 8);
        a3 += __shfl_xor(a3, 1); a3 += __shfl_xor(a3, 2); a3 += __shfl_xor(a3, 4); a3 += __shfl_xor(a3, 8);
        if (p == 0) {
            float* g = gh_lds[t & 1];
            g[rg * 4 + 0] = a0;
            g[rg * 4 + 1] = a1;
            g[rg * 4 + 2] = a2;
            g[rg * 4 + 3] = a3;
        }
        __syncthreads();   // gh_lds[t&1] complete; other waves run ahead to t+1

        if (tid < 64) {    // wave 0: combine + publish
            if (tid < 32) {
                const float* g = gh_lds[t & 1];
                float hr = g[tid], hz = g[32 + tid], hn = g[64 + tid];
                float rr = 1.f / (1.f + __expf(-(xr + hr + bR)));
                float zz = 1.f / (1.f + __expf(-(xz + hz + bZ)));
                float nn = tanhf(xn + rr * (hn + bN));
                float hnew = (1.f - zz) * nn + zz * hprev;
                float* hnx = hb + ((t + 1) & 1) * HID;
                __hip_atomic_store(&hnx[ch0 + tid], hnew, __ATOMIC_RELAXED, SCOPE_SYS);
                hseq[(brow + t) * HID + ch0 + tid] = hnew + skv;
            }
            // release: h slice at coherent point before flag becomes visible
            asm volatile("s_waitcnt vmcnt(0)" ::: "memory");
            if (tid == 0)
                __hip_atomic_store(&flg[wg], t + 1, __ATOMIC_RELAXED, SCOPE_SYS);
        }
    }
}

// ---------------------------------------------------------------------------
extern "C" void kernel_launch(void* const* d_in, const int* in_sizes, int n_in,
                              void* d_out, int out_size, void* d_ws, size_t ws_size,
                              hipStream_t stream) {
    (void)in_sizes; (void)n_in; (void)out_size; (void)ws_size;
    const float* x         = (const float*)d_in[0];
    const float* mels      = (const float*)d_in[1];
    const float* conv_in_w = (const float*)d_in[2];
    const float* bn0_g     = (const float*)d_in[3];
    const float* bn0_b     = (const float*)d_in[4];
    const float* res_c1    = (const float*)d_in[5];
    const float* res_c2    = (const float*)d_in[6];
    const float* res_bn1_g = (const float*)d_in[7];
    const float* res_bn1_b = (const float*)d_in[8];
    const float* res_bn2_g = (const float*)d_in[9];
    const float* res_bn2_b = (const float*)d_in[10];
    const float* conv_out_w= (const float*)d_in[11];
    const float* conv_out_b= (const float*)d_in[12];
    const float* up_w0     = (const float*)d_in[13];
    const float* up_w1     = (const float*)d_in[14];
    const float* up_w2     = (const float*)d_in[15];
    const float* I_w       = (const float*)d_in[16];
    const float* I_b       = (const float*)d_in[17];
    const float* r1_wih    = (const float*)d_in[18];
    const float* r1_whh    = (const float*)d_in[19];
    const float* r1_bih    = (const float*)d_in[20];
    const float* r1_bhh    = (const float*)d_in[21];
    const float* r2_wih    = (const float*)d_in[22];
    const float* r2_whh    = (const float*)d_in[23];
    const float* r2_bih    = (const float*)d_in[24];
    const float* r2_bhh    = (const float*)d_in[25];
    const float* fc1_w     = (const float*)d_in[26];
    const float* fc1_b     = (const float*)d_in[27];
    const float* fc2_w     = (const float*)d_in[28];
    const float* fc2_b     = (const float*)d_in[29];
    const float* fc3_w     = (const float*)d_in[30];
    const float* fc3_b     = (const float*)d_in[31];

    char* ws = (char*)d_ws;
    size_t off = 0;
    auto alloc = [&](size_t bytes) {
        char* p = ws + off;
        off += (bytes + 255) & ~(size_t)255;
        return p;
    };
    int*   flags1 = (int*)  alloc(256);
    int*   flags2 = (int*)  alloc(256);
    float* hbuf1  = (float*)alloc(4 * 2 * HID * 4);
    float* hbuf2  = (float*)alloc(4 * 2 * HID * 4);
    float* rnA    = (float*)alloc((size_t)BATCH * CCH * LRES * 4);
    float* rnB    = (float*)alloc((size_t)BATCH * CCH * LRES * 4);
    float* aux_s  = (float*)alloc((size_t)BATCH * CCH * LRES * 4);
    float* s1     = (float*)alloc((size_t)BATCH * NFEAT * 216 * 4);
    float* s2     = (float*)alloc((size_t)BATCH * NFEAT * 1728 * 4);
    float* mup    = (float*)alloc((size_t)BATCH * T_LEN * NFEAT * 4);
    float* auxt   = (float*)alloc((size_t)BATCH * T_LEN * CCH * 4);
    float* h0     = (float*)alloc((size_t)M_ROWS * HID * 4);
    float* xp     = (float*)alloc((size_t)M_ROWS * 1536 * 4);
    float* h1     = (float*)alloc((size_t)M_ROWS * HID * 4);
    float* h2     = (float*)alloc((size_t)M_ROWS * HID * 4);
    float* f1 = h0;   // h0 dead after GRU1
    float* f2 = h1;   // h1 dead after GRU2

    hipMemsetAsync(flags1, 0, 512, stream);   // flags1+flags2 contiguous

    // mel resnet
    k_conv_in<<<BATCH * LRES, 128, 0, stream>>>(mels, conv_in_w, bn0_g, bn0_b, rnA);
    for (int i = 0; i < 10; ++i) {
        k_ein<0><<<BATCH * LRES, 128, 0, stream>>>(rnA, res_c1 + (size_t)i * CCH * CCH,
            res_bn1_g + i * CCH, res_bn1_b + i * CCH, nullptr, rnB);
        k_ein<1><<<BATCH * LRES, 128, 0, stream>>>(rnB, res_c2 + (size_t)i * CCH * CCH,
            res_bn2_g + i * CCH, res_bn2_b + i * CCH, rnA, rnA);
    }
    k_ein<2><<<BATCH * LRES, 128, 0, stream>>>(rnA, conv_out_w, nullptr, conv_out_b, nullptr, aux_s);
    k_auxrep<<<(BATCH * T_LEN * CCH) / 256, 256, 0, stream>>>(aux_s, auxt);

    // upsample
    k_up1<<<(BATCH * NFEAT * 216) / 256, 256, 0, stream>>>(mels, up_w0, s1);
    k_up2<<<(BATCH * NFEAT * 1728) / 256, 256, 0, stream>>>(s1, up_w1, s2);
    k_up3<<<(BATCH * T_LEN * NFEAT) / 256, 256, 0, stream>>>(s2, up_w2, mup);

    // h0 = concat(x, m_up, a1) @ I_w^T + I_b
    gemm_f32<0><<<dim3(512 / 128, M_ROWS / 128), 256, 0, stream>>>(
        x, 1, 1, mup, NFEAT, NFEAT, auxt, CCH, 32, I_w, I_b, h0, 512, 113);
    // xp1 = h0 @ r1_wih^T + r1_bih
    gemm_f32<0><<<dim3(1536 / 128, M_ROWS / 128), 256, 0, stream>>>(
        h0, HID, HID, nullptr, 0, 0, nullptr, 0, 0, r1_wih, r1_bih, xp, 1536, 512);
    // GRU1 (writes h1 = gru + h0)
    k_gru<<<128, 384, 0, stream>>>(xp, r1_whh, r1_bhh, h0, h1, hbuf1, flags1);
    // xp2 = concat(h1, a2) @ r2_wih^T + r2_bih
    gemm_f32<0><<<dim3(1536 / 128, M_ROWS / 128), 256, 0, stream>>>(
        h1, HID, HID, auxt + 32, CCH, 32, nullptr, 0, 0, r2_wih, r2_bih, xp, 1536, 544);
    // GRU2 (writes h2 = gru + h1)
    k_gru<<<128, 384, 0, stream>>>(xp, r2_whh, r2_bhh, h1, h2, hbuf2, flags2);
    // fc chain
    gemm_f32<1><<<dim3(512 / 128, M_ROWS / 128), 256, 0, stream>>>(
        h2, HID, HID, auxt + 64, CCH, 32, nullptr, 0, 0, fc1_w, fc1_b, f1, 512, 544);
    gemm_f32<1><<<dim3(512 / 128, M_ROWS / 128), 256, 0, stream>>>(
        f1, HID, HID, auxt + 96, CCH, 32, nullptr, 0, 0, fc2_w, fc2_b, f2, 512, 544);
    gemm_f32<0><<<dim3(1024 / 128, M_ROWS / 128), 256, 0, stream>>>(
        f2, HID, HID, nullptr, 0, 0, nullptr, 0, 0, fc3_w, fc3_b, (float*)d_out, 1024, 512);
}

// Round 4
// 64552.625 us; speedup vs baseline: 5.7548x; 2.9770x over previous
//
#include <hip/hip_runtime.h>

#define T_LEN  12800
#define BATCH  4
#define HID    512
#define NFEAT  80
#define FRAMES 54
#define CCH    128
#define LRES   50
#define M_ROWS (BATCH * T_LEN)   // 51200

#define SCOPE_SYS __HIP_MEMORY_SCOPE_SYSTEM

// ---------------------------------------------------------------------------
// mel resnet: conv_in (K=5, VALID) + bn0 + relu
// ---------------------------------------------------------------------------
__global__ __launch_bounds__(128)
void k_conv_in(const float* __restrict__ mels, const float* __restrict__ w,
               const float* __restrict__ g, const float* __restrict__ bb,
               float* __restrict__ out) {
    int blk = blockIdx.x;            // b*LRES + l
    int b = blk / LRES, l = blk % LRES;
    int o = threadIdx.x;
    __shared__ float ms[NFEAT * 5];
    for (int i = o; i < NFEAT * 5; i += 128) {
        int c = i / 5, k = i % 5;
        ms[i] = mels[(b * NFEAT + c) * FRAMES + l + k];
    }
    __syncthreads();
    const float* wr = w + o * NFEAT * 5;
    float s = 0.f;
    for (int i = 0; i < NFEAT * 5; ++i) s = fmaf(ms[i], wr[i], s);
    float inv = g[o] * rsqrtf(1.f + 1e-5f);
    s = s * inv + bb[o];
    out[(b * CCH + o) * LRES + l] = fmaxf(s, 0.f);
}

// einsum 'bcl,oc->bol' (+bn variants). MODE 0: bn+relu; 1: bn + residual; 2: +bias
template <int MODE>
__global__ __launch_bounds__(128)
void k_ein(const float* __restrict__ x, const float* __restrict__ w,
           const float* __restrict__ g, const float* __restrict__ bb,
           const float* __restrict__ res, float* __restrict__ out) {
    int blk = blockIdx.x;
    int b = blk / LRES, l = blk % LRES;
    int o = threadIdx.x;
    __shared__ float xs[CCH];
    xs[o] = x[(b * CCH + o) * LRES + l];
    __syncthreads();
    const float* wr = w + o * CCH;
    float s = 0.f;
#pragma unroll 8
    for (int c = 0; c < CCH; ++c) s = fmaf(xs[c], wr[c], s);
    float v;
    if (MODE == 2) {
        v = s + bb[o];
    } else {
        float inv = g[o] * rsqrtf(1.f + 1e-5f);
        v = s * inv + bb[o];
        if (MODE == 0) v = fmaxf(v, 0.f);
        else           v = v + res[(b * CCH + o) * LRES + l];
    }
    out[(b * CCH + o) * LRES + l] = v;
}

// aux repeat: aux_t[b][t][ch] = aux_small[b][ch][t>>8]
__global__ __launch_bounds__(256)
void k_auxrep(const float* __restrict__ aux_s, float* __restrict__ aux_t) {
    int idx = blockIdx.x * 256 + threadIdx.x;   // < B*T*128 (exact)
    int ch = idx & 127;
    int bt = idx >> 7;
    int t = bt % T_LEN, b = bt / T_LEN;
    aux_t[idx] = aux_s[(b * CCH + ch) * LRES + (t >> 8)];
}

// ---------------------------------------------------------------------------
// upsample: 3 repeat+conv stages
// ---------------------------------------------------------------------------
__global__ __launch_bounds__(256)
void k_up1(const float* __restrict__ mels, const float* __restrict__ w0, float* __restrict__ s1) {
    int idx = blockIdx.x * 256 + threadIdx.x;  // B*80*216 exact
    int i = idx % 216; int bc = idx / 216;
    float s = 0.f;
#pragma unroll
    for (int k = 0; k < 9; ++k) {
        int q = i + k - 4;
        if (q >= 0 && q < 216) s = fmaf(w0[k], mels[bc * FRAMES + (q >> 2)], s);
    }
    s1[idx] = s;
}
__global__ __launch_bounds__(256)
void k_up2(const float* __restrict__ s1, const float* __restrict__ w1, float* __restrict__ s2) {
    int idx = blockIdx.x * 256 + threadIdx.x;  // B*80*1728 exact
    int j = idx % 1728; int bc = idx / 1728;
    float s = 0.f;
#pragma unroll
    for (int k = 0; k < 17; ++k) {
        int q = j + k - 8;
        if (q >= 0 && q < 1728) s = fmaf(w1[k], s1[bc * 216 + (q >> 3)], s);
    }
    s2[idx] = s;
}
__global__ __launch_bounds__(256)
void k_up3(const float* __restrict__ s2, const float* __restrict__ w2, float* __restrict__ mup) {
    int idx = blockIdx.x * 256 + threadIdx.x;  // B*T*80 exact
    int c = idx % NFEAT; int bt = idx / NFEAT;
    int t = bt % T_LEN; int b = bt / T_LEN;
    const float* src = s2 + (b * NFEAT + c) * 1728;
    float s = 0.f;
#pragma unroll
    for (int k = 0; k < 17; ++k) s = fmaf(w2[k], src[(t + 504 + k) >> 3], s);
    mup[idx] = s;
}

// ---------------------------------------------------------------------------
// fp32 GEMM: C[M,N] = act( concat(A1,A2,A3) @ W[N,K]^T + bias )
// tile 128x128, BK=8, 256 threads, 8x8 per thread. Grid: (N/128, M/128).
// ---------------------------------------------------------------------------
template <int ACT>
__global__ __launch_bounds__(256)
void gemm_f32(const float* __restrict__ A1, int lda1, int K1,
              const float* __restrict__ A2, int lda2, int K2,
              const float* __restrict__ A3, int lda3, int K3,
              const float* __restrict__ W, const float* __restrict__ bias,
              float* __restrict__ C, int N, int K) {
    __shared__ float As[8][128];
    __shared__ float Bs[8][128];
    int tid = threadIdx.x;
    int n0 = blockIdx.x * 128, m0 = blockIdx.y * 128;
    int tx = tid & 15, ty = tid >> 4;
    int row = tid >> 1;
    int kc = (tid & 1) * 4;
    float acc[8][8];
#pragma unroll
    for (int r = 0; r < 8; ++r)
#pragma unroll
        for (int c = 0; c < 8; ++c) acc[r][c] = 0.f;

    for (int k0 = 0; k0 < K; k0 += 8) {
#pragma unroll
        for (int e = 0; e < 4; ++e) {
            int gk = k0 + kc + e;
            int m = m0 + row;
            float v = 0.f;
            if (gk < K1)            v = A1[(size_t)m * lda1 + gk];
            else if (gk < K1 + K2)  v = A2[(size_t)m * lda2 + (gk - K1)];
            else if (gk < K)        v = A3[(size_t)m * lda3 + (gk - K1 - K2)];
            As[kc + e][row] = v;
            float wv = (gk < K) ? W[(size_t)(n0 + row) * K + gk] : 0.f;
            Bs[kc + e][row] = wv;
        }
        __syncthreads();
#pragma unroll
        for (int kk = 0; kk < 8; ++kk) {
            float a[8], bv[8];
#pragma unroll
            for (int h = 0; h < 2; ++h) {
                float4 t4 = *(const float4*)&As[kk][ty * 8 + h * 4];
                a[h * 4 + 0] = t4.x; a[h * 4 + 1] = t4.y; a[h * 4 + 2] = t4.z; a[h * 4 + 3] = t4.w;
                float4 u4 = *(const float4*)&Bs[kk][tx * 8 + h * 4];
                bv[h * 4 + 0] = u4.x; bv[h * 4 + 1] = u4.y; bv[h * 4 + 2] = u4.z; bv[h * 4 + 3] = u4.w;
            }
#pragma unroll
            for (int r = 0; r < 8; ++r)
#pragma unroll
                for (int c = 0; c < 8; ++c) acc[r][c] = fmaf(a[r], bv[c], acc[r][c]);
        }
        __syncthreads();
    }
#pragma unroll
    for (int r = 0; r < 8; ++r) {
        int m = m0 + ty * 8 + r;
        float* co = C + (size_t)m * N + n0 + tx * 8;
#pragma unroll
        for (int c = 0; c < 8; ++c) {
            float v = acc[r][c] + bias[n0 + tx * 8 + c];
            if (ACT) v = fmaxf(v, 0.f);
            co[c] = v;
        }
    }
}

// ---------------------------------------------------------------------------
// Persistent GRU recurrence, v3. 4 clusters (one per batch) x 16 WGs x 384 thr.
// Per step: ONLY wave 0 polls the cluster's 16 flags (one 64B line) and pulls
// h (8 coalesced sys-scope loads/lane) into padded LDS; waves 1-5 sleep at the
// barrier. All waves then ds_read fragments, FMA against register-resident
// weights, shuffle-reduce, and wave 0 combines + publishes (sc0sc1 stores,
// vmcnt(0) release, flag store). No __threadfence anywhere.
// ---------------------------------------------------------------------------
__global__ __launch_bounds__(384)
void k_gru(const float* __restrict__ xp, const float* __restrict__ whh,
           const float* __restrict__ bhh, const float* __restrict__ skip,
           float* __restrict__ hseq, float* hbuf, int* flags) {
    int blk = blockIdx.x;
    int cb = blk & 7;               // cluster (=batch); one XCD under round-robin
    if (cb >= BATCH) return;
    int wg = blk >> 3;              // 0..15
    int tid = threadIdx.x;
    int ch0 = wg * 32;
    int rg = tid >> 4;              // 0..23 (4 gate-rows each)
    int p = tid & 15;               // 32-wide k chunk

    float* hb = hbuf + cb * 2 * HID;
    int* flg = flags + cb * 16;

    // resident weights: rows lr = rg*4+j -> R = (lr>>5)*512 + ch0 + (lr&31)
    float w[128];
#pragma unroll
    for (int j = 0; j < 4; ++j) {
        int lr = rg * 4 + j;
        int R = (lr >> 5) * HID + ch0 + (lr & 31);
        const float* src = whh + (size_t)R * HID + p * 32;
#pragma unroll
        for (int q = 0; q < 8; ++q) {
            float4 v = *(const float4*)&src[q * 4];
            w[j * 32 + q * 4 + 0] = v.x; w[j * 32 + q * 4 + 1] = v.y;
            w[j * 32 + q * 4 + 2] = v.z; w[j * 32 + q * 4 + 3] = v.w;
        }
    }
    float bR = 0.f, bZ = 0.f, bN = 0.f;
    if (tid < 32) {
        bR = bhh[ch0 + tid];
        bZ = bhh[HID + ch0 + tid];
        bN = bhh[2 * HID + ch0 + tid];
    }

    // h staged in LDS: 16 chunks of 32 floats, +4 pad per chunk (bank spread)
    __shared__ float h_lds[16 * 36];
    __shared__ float gh_lds[96];
    const size_t brow = (size_t)cb * T_LEN;
    int spin_budget = 1 << 22;      // lifetime anti-hang budget

    for (int t = 0; t < T_LEN; ++t) {
        // prefetch step inputs (no dependence on h) — normal cached loads,
        // issued before the poll so latency hides under it
        float xr = 0.f, xz = 0.f, xn = 0.f, skv = 0.f;
        if (tid < 32) {
            const float* xpt = xp + (brow + t) * 1536;
            xr = xpt[ch0 + tid];
            xz = xpt[HID + ch0 + tid];
            xn = xpt[2 * HID + ch0 + tid];
            skv = skip[(brow + t) * HID + ch0 + tid];
        }

        if (t == 0) {
            // zero h_lds (all threads; pad included)
            h_lds[tid] = 0.f;
            if (tid < 192) h_lds[384 + tid] = 0.f;
        } else if (tid < 64) {
            // wave 0 only: poll all 16 flags (single 64B line)
            while (true) {
                int v = (tid < 16)
                    ? __hip_atomic_load(&flg[tid], __ATOMIC_RELAXED, SCOPE_SYS)
                    : t;
                if (__all(v >= t)) break;
                if (--spin_budget < 0) break;
            }
            __builtin_amdgcn_sched_barrier(0);   // keep h pull after the poll
            // coalesced sys-scope pull of h (8 x 64-lane contiguous loads)
            const float* hc = hb + (t & 1) * HID;
            float hv[8];
#pragma unroll
            for (int j = 0; j < 8; ++j)
                hv[j] = __hip_atomic_load(&hc[tid + 64 * j], __ATOMIC_RELAXED, SCOPE_SYS);
            // stage to padded LDS
#pragma unroll
            for (int j = 0; j < 8; ++j) {
                int i = tid + 64 * j;
                h_lds[(i >> 5) * 36 + (i & 31)] = hv[j];
            }
        }
        __syncthreads();   // barrier 1: h_lds ready (waves 1-5 slept here)

        // dot: 4 gate-rows x 32-wide chunk, h from LDS (2-way aliasing = free)
        float a0 = 0.f, a1 = 0.f, a2 = 0.f, a3 = 0.f;
#pragma unroll
        for (int q = 0; q < 8; ++q) {
            float4 hv4 = *(const float4*)&h_lds[p * 36 + q * 4];
            float hh[4] = {hv4.x, hv4.y, hv4.z, hv4.w};
#pragma unroll
            for (int e = 0; e < 4; ++e) {
                int i = q * 4 + e;
                a0 = fmaf(w[i],      hh[e], a0);
                a1 = fmaf(w[32 + i], hh[e], a1);
                a2 = fmaf(w[64 + i], hh[e], a2);
                a3 = fmaf(w[96 + i], hh[e], a3);
            }
        }
        a0 += __shfl_xor(a0, 1); a0 += __shfl_xor(a0, 2); a0 += __shfl_xor(a0, 4); a0 += __shfl_xor(a0, 8);
        a1 += __shfl_xor(a1, 1); a1 += __shfl_xor(a1, 2); a1 += __shfl_xor(a1, 4); a1 += __shfl_xor(a1, 8);
        a2 += __shfl_xor(a2, 1); a2 += __shfl_xor(a2, 2); a2 += __shfl_xor(a2, 4); a2 += __shfl_xor(a2, 8);
        a3 += __shfl_xor(a3, 1); a3 += __shfl_xor(a3, 2); a3 += __shfl_xor(a3, 4); a3 += __shfl_xor(a3, 8);
        if (p == 0) {
            gh_lds[rg * 4 + 0] = a0;
            gh_lds[rg * 4 + 1] = a1;
            gh_lds[rg * 4 + 2] = a2;
            gh_lds[rg * 4 + 3] = a3;
        }
        __syncthreads();   // barrier 2: gh_lds complete

        if (tid < 64) {    // wave 0: combine + publish
            if (tid < 32) {
                float hr = gh_lds[tid], hz = gh_lds[32 + tid], hn = gh_lds[64 + tid];
                float rr = __fdividef(1.f, 1.f + __expf(-(xr + hr + bR)));
                float zz = __fdividef(1.f, 1.f + __expf(-(xz + hz + bZ)));
                float ax = xn + rr * (hn + bN);
                float e2 = __expf(2.f * ax);
                float nn = 1.f - __fdividef(2.f, e2 + 1.f);   // tanh(ax)
                float hprev = h_lds[wg * 36 + tid];
                float hnew = (1.f - zz) * nn + zz * hprev;
                float* hnx = hb + ((t + 1) & 1) * HID;
                __hip_atomic_store(&hnx[ch0 + tid], hnew, __ATOMIC_RELAXED, SCOPE_SYS);
                hseq[(brow + t) * HID + ch0 + tid] = hnew + skv;
            }
            // release: h slice at coherence point before flag becomes visible
            asm volatile("s_waitcnt vmcnt(0)" ::: "memory");
            if (tid == 0)
                __hip_atomic_store(&flg[wg], t + 1, __ATOMIC_RELAXED, SCOPE_SYS);
        }
    }
}

// ---------------------------------------------------------------------------
extern "C" void kernel_launch(void* const* d_in, const int* in_sizes, int n_in,
                              void* d_out, int out_size, void* d_ws, size_t ws_size,
                              hipStream_t stream) {
    (void)in_sizes; (void)n_in; (void)out_size; (void)ws_size;
    const float* x         = (const float*)d_in[0];
    const float* mels      = (const float*)d_in[1];
    const float* conv_in_w = (const float*)d_in[2];
    const float* bn0_g     = (const float*)d_in[3];
    const float* bn0_b     = (const float*)d_in[4];
    const float* res_c1    = (const float*)d_in[5];
    const float* res_c2    = (const float*)d_in[6];
    const float* res_bn1_g = (const float*)d_in[7];
    const float* res_bn1_b = (const float*)d_in[8];
    const float* res_bn2_g = (const float*)d_in[9];
    const float* res_bn2_b = (const float*)d_in[10];
    const float* conv_out_w= (const float*)d_in[11];
    const float* conv_out_b= (const float*)d_in[12];
    const float* up_w0     = (const float*)d_in[13];
    const float* up_w1     = (const float*)d_in[14];
    const float* up_w2     = (const float*)d_in[15];
    const float* I_w       = (const float*)d_in[16];
    const float* I_b       = (const float*)d_in[17];
    const float* r1_wih    = (const float*)d_in[18];
    const float* r1_whh    = (const float*)d_in[19];
    const float* r1_bih    = (const float*)d_in[20];
    const float* r1_bhh    = (const float*)d_in[21];
    const float* r2_wih    = (const float*)d_in[22];
    const float* r2_whh    = (const float*)d_in[23];
    const float* r2_bih    = (const float*)d_in[24];
    const float* r2_bhh    = (const float*)d_in[25];
    const float* fc1_w     = (const float*)d_in[26];
    const float* fc1_b     = (const float*)d_in[27];
    const float* fc2_w     = (const float*)d_in[28];
    const float* fc2_b     = (const float*)d_in[29];
    const float* fc3_w     = (const float*)d_in[30];
    const float* fc3_b     = (const float*)d_in[31];

    char* ws = (char*)d_ws;
    size_t off = 0;
    auto alloc = [&](size_t bytes) {
        char* p = ws + off;
        off += (bytes + 255) & ~(size_t)255;
        return p;
    };
    int*   flags1 = (int*)  alloc(256);
    int*   flags2 = (int*)  alloc(256);
    float* hbuf1  = (float*)alloc(4 * 2 * HID * 4);
    float* hbuf2  = (float*)alloc(4 * 2 * HID * 4);
    float* rnA    = (float*)alloc((size_t)BATCH * CCH * LRES * 4);
    float* rnB    = (float*)alloc((size_t)BATCH * CCH * LRES * 4);
    float* aux_s  = (float*)alloc((size_t)BATCH * CCH * LRES * 4);
    float* s1     = (float*)alloc((size_t)BATCH * NFEAT * 216 * 4);
    float* s2     = (float*)alloc((size_t)BATCH * NFEAT * 1728 * 4);
    float* mup    = (float*)alloc((size_t)BATCH * T_LEN * NFEAT * 4);
    float* auxt   = (float*)alloc((size_t)BATCH * T_LEN * CCH * 4);
    float* h0     = (float*)alloc((size_t)M_ROWS * HID * 4);
    float* xp     = (float*)alloc((size_t)M_ROWS * 1536 * 4);
    float* h1     = (float*)alloc((size_t)M_ROWS * HID * 4);
    float* h2     = (float*)alloc((size_t)M_ROWS * HID * 4);
    float* f1 = h0;   // h0 dead after GRU1
    float* f2 = h1;   // h1 dead after GRU2

    hipMemsetAsync(flags1, 0, 512, stream);   // flags1+flags2 contiguous

    // mel resnet
    k_conv_in<<<BATCH * LRES, 128, 0, stream>>>(mels, conv_in_w, bn0_g, bn0_b, rnA);
    for (int i = 0; i < 10; ++i) {
        k_ein<0><<<BATCH * LRES, 128, 0, stream>>>(rnA, res_c1 + (size_t)i * CCH * CCH,
            res_bn1_g + i * CCH, res_bn1_b + i * CCH, nullptr, rnB);
        k_ein<1><<<BATCH * LRES, 128, 0, stream>>>(rnB, res_c2 + (size_t)i * CCH * CCH,
            res_bn2_g + i * CCH, res_bn2_b + i * CCH, rnA, rnA);
    }
    k_ein<2><<<BATCH * LRES, 128, 0, stream>>>(rnA, conv_out_w, nullptr, conv_out_b, nullptr, aux_s);
    k_auxrep<<<(BATCH * T_LEN * CCH) / 256, 256, 0, stream>>>(aux_s, auxt);

    // upsample
    k_up1<<<(BATCH * NFEAT * 216) / 256, 256, 0, stream>>>(mels, up_w0, s1);
    k_up2<<<(BATCH * NFEAT * 1728) / 256, 256, 0, stream>>>(s1, up_w1, s2);
    k_up3<<<(BATCH * T_LEN * NFEAT) / 256, 256, 0, stream>>>(s2, up_w2, mup);

    // h0 = concat(x, m_up, a1) @ I_w^T + I_b
    gemm_f32<0><<<dim3(512 / 128, M_ROWS / 128), 256, 0, stream>>>(
        x, 1, 1, mup, NFEAT, NFEAT, auxt, CCH, 32, I_w, I_b, h0, 512, 113);
    // xp1 = h0 @ r1_wih^T + r1_bih
    gemm_f32<0><<<dim3(1536 / 128, M_ROWS / 128), 256, 0, stream>>>(
        h0, HID, HID, nullptr, 0, 0, nullptr, 0, 0, r1_wih, r1_bih, xp, 1536, 512);
    // GRU1 (writes h1 = gru + h0)
    k_gru<<<128, 384, 0, stream>>>(xp, r1_whh, r1_bhh, h0, h1, hbuf1, flags1);
    // xp2 = concat(h1, a2) @ r2_wih^T + r2_bih
    gemm_f32<0><<<dim3(1536 / 128, M_ROWS / 128), 256, 0, stream>>>(
        h1, HID, HID, auxt + 32, CCH, 32, nullptr, 0, 0, r2_wih, r2_bih, xp, 1536, 544);
    // GRU2 (writes h2 = gru + h1)
    k_gru<<<128, 384, 0, stream>>>(xp, r2_whh, r2_bhh, h1, h2, hbuf2, flags2);
    // fc chain
    gemm_f32<1><<<dim3(512 / 128, M_ROWS / 128), 256, 0, stream>>>(
        h2, HID, HID, auxt + 64, CCH, 32, nullptr, 0, 0, fc1_w, fc1_b, f1, 512, 544);
    gemm_f32<1><<<dim3(512 / 128, M_ROWS / 128), 256, 0, stream>>>(
        f1, HID, HID, auxt + 96, CCH, 32, nullptr, 0, 0, fc2_w, fc2_b, f2, 512, 544);
    gemm_f32<0><<<dim3(1024 / 128, M_ROWS / 128), 256, 0, stream>>>(
        f2, HID, HID, nullptr, 0, 0, nullptr, 0, 0, fc3_w, fc3_b, (float*)d_out, 1024, 512);
}

// Round 5
// 58058.954 us; speedup vs baseline: 6.3985x; 1.1118x over previous
//
#include <hip/hip_runtime.h>

#define T_LEN  12800
#define BATCH  4
#define HID    512
#define NFEAT  80
#define FRAMES 54
#define CCH    128
#define LRES   50
#define M_ROWS (BATCH * T_LEN)   // 51200
#define RING   64                // xp2 ring depth (steps)
#define NWRK   24                // xp2 worker WGs (64 out-channels each)

#define SCOPE_SYS __HIP_MEMORY_SCOPE_SYSTEM

// ---------------------------------------------------------------------------
// mel resnet: conv_in (K=5, VALID) + bn0 + relu
// ---------------------------------------------------------------------------
__global__ __launch_bounds__(128)
void k_conv_in(const float* __restrict__ mels, const float* __restrict__ w,
               const float* __restrict__ g, const float* __restrict__ bb,
               float* __restrict__ out) {
    int blk = blockIdx.x;            // b*LRES + l
    int b = blk / LRES, l = blk % LRES;
    int o = threadIdx.x;
    __shared__ float ms[NFEAT * 5];
    for (int i = o; i < NFEAT * 5; i += 128) {
        int c = i / 5, k = i % 5;
        ms[i] = mels[(b * NFEAT + c) * FRAMES + l + k];
    }
    __syncthreads();
    const float* wr = w + o * NFEAT * 5;
    float s = 0.f;
    for (int i = 0; i < NFEAT * 5; ++i) s = fmaf(ms[i], wr[i], s);
    float inv = g[o] * rsqrtf(1.f + 1e-5f);
    s = s * inv + bb[o];
    out[(b * CCH + o) * LRES + l] = fmaxf(s, 0.f);
}

// einsum 'bcl,oc->bol' (+bn variants). MODE 0: bn+relu; 1: bn + residual; 2: +bias
template <int MODE>
__global__ __launch_bounds__(128)
void k_ein(const float* __restrict__ x, const float* __restrict__ w,
           const float* __restrict__ g, const float* __restrict__ bb,
           const float* __restrict__ res, float* __restrict__ out) {
    int blk = blockIdx.x;
    int b = blk / LRES, l = blk % LRES;
    int o = threadIdx.x;
    __shared__ float xs[CCH];
    xs[o] = x[(b * CCH + o) * LRES + l];
    __syncthreads();
    const float* wr = w + o * CCH;
    float s = 0.f;
#pragma unroll 8
    for (int c = 0; c < CCH; ++c) s = fmaf(xs[c], wr[c], s);
    float v;
    if (MODE == 2) {
        v = s + bb[o];
    } else {
        float inv = g[o] * rsqrtf(1.f + 1e-5f);
        v = s * inv + bb[o];
        if (MODE == 0) v = fmaxf(v, 0.f);
        else           v = v + res[(b * CCH + o) * LRES + l];
    }
    out[(b * CCH + o) * LRES + l] = v;
}

// aux repeat: aux_t[b][t][ch] = aux_small[b][ch][t>>8]
__global__ __launch_bounds__(256)
void k_auxrep(const float* __restrict__ aux_s, float* __restrict__ aux_t) {
    int idx = blockIdx.x * 256 + threadIdx.x;   // < B*T*128 (exact)
    int ch = idx & 127;
    int bt = idx >> 7;
    int t = bt % T_LEN, b = bt / T_LEN;
    aux_t[idx] = aux_s[(b * CCH + ch) * LRES + (t >> 8)];
}

// ---------------------------------------------------------------------------
// upsample: 3 repeat+conv stages
// ---------------------------------------------------------------------------
__global__ __launch_bounds__(256)
void k_up1(const float* __restrict__ mels, const float* __restrict__ w0, float* __restrict__ s1) {
    int idx = blockIdx.x * 256 + threadIdx.x;  // B*80*216 exact
    int i = idx % 216; int bc = idx / 216;
    float s = 0.f;
#pragma unroll
    for (int k = 0; k < 9; ++k) {
        int q = i + k - 4;
        if (q >= 0 && q < 216) s = fmaf(w0[k], mels[bc * FRAMES + (q >> 2)], s);
    }
    s1[idx] = s;
}
__global__ __launch_bounds__(256)
void k_up2(const float* __restrict__ s1, const float* __restrict__ w1, float* __restrict__ s2) {
    int idx = blockIdx.x * 256 + threadIdx.x;  // B*80*1728 exact
    int j = idx % 1728; int bc = idx / 1728;
    float s = 0.f;
#pragma unroll
    for (int k = 0; k < 17; ++k) {
        int q = j + k - 8;
        if (q >= 0 && q < 1728) s = fmaf(w1[k], s1[bc * 216 + (q >> 3)], s);
    }
    s2[idx] = s;
}
__global__ __launch_bounds__(256)
void k_up3(const float* __restrict__ s2, const float* __restrict__ w2, float* __restrict__ mup) {
    int idx = blockIdx.x * 256 + threadIdx.x;  // B*T*80 exact
    int c = idx % NFEAT; int bt = idx / NFEAT;
    int t = bt % T_LEN; int b = bt / T_LEN;
    const float* src = s2 + (b * NFEAT + c) * 1728;
    float s = 0.f;
#pragma unroll
    for (int k = 0; k < 17; ++k) s = fmaf(w2[k], src[(t + 504 + k) >> 3], s);
    mup[idx] = s;
}

// ---------------------------------------------------------------------------
// fp32 GEMM: C[M,N] = act( concat(A1,A2,A3) @ W[N,K]^T + bias )
// tile 128x128, BK=8, 256 threads, 8x8 per thread. Grid: (N/128, M/128).
// ---------------------------------------------------------------------------
template <int ACT>
__global__ __launch_bounds__(256)
void gemm_f32(const float* __restrict__ A1, int lda1, int K1,
              const float* __restrict__ A2, int lda2, int K2,
              const float* __restrict__ A3, int lda3, int K3,
              const float* __restrict__ W, const float* __restrict__ bias,
              float* __restrict__ C, int N, int K) {
    __shared__ float As[8][128];
    __shared__ float Bs[8][128];
    int tid = threadIdx.x;
    int n0 = blockIdx.x * 128, m0 = blockIdx.y * 128;
    int tx = tid & 15, ty = tid >> 4;
    int row = tid >> 1;
    int kc = (tid & 1) * 4;
    float acc[8][8];
#pragma unroll
    for (int r = 0; r < 8; ++r)
#pragma unroll
        for (int c = 0; c < 8; ++c) acc[r][c] = 0.f;

    for (int k0 = 0; k0 < K; k0 += 8) {
#pragma unroll
        for (int e = 0; e < 4; ++e) {
            int gk = k0 + kc + e;
            int m = m0 + row;
            float v = 0.f;
            if (gk < K1)            v = A1[(size_t)m * lda1 + gk];
            else if (gk < K1 + K2)  v = A2[(size_t)m * lda2 + (gk - K1)];
            else if (gk < K)        v = A3[(size_t)m * lda3 + (gk - K1 - K2)];
            As[kc + e][row] = v;
            float wv = (gk < K) ? W[(size_t)(n0 + row) * K + gk] : 0.f;
            Bs[kc + e][row] = wv;
        }
        __syncthreads();
#pragma unroll
        for (int kk = 0; kk < 8; ++kk) {
            float a[8], bv[8];
#pragma unroll
            for (int h = 0; h < 2; ++h) {
                float4 t4 = *(const float4*)&As[kk][ty * 8 + h * 4];
                a[h * 4 + 0] = t4.x; a[h * 4 + 1] = t4.y; a[h * 4 + 2] = t4.z; a[h * 4 + 3] = t4.w;
                float4 u4 = *(const float4*)&Bs[kk][tx * 8 + h * 4];
                bv[h * 4 + 0] = u4.x; bv[h * 4 + 1] = u4.y; bv[h * 4 + 2] = u4.z; bv[h * 4 + 3] = u4.w;
            }
#pragma unroll
            for (int r = 0; r < 8; ++r)
#pragma unroll
                for (int c = 0; c < 8; ++c) acc[r][c] = fmaf(a[r], bv[c], acc[r][c]);
        }
        __syncthreads();
    }
#pragma unroll
    for (int r = 0; r < 8; ++r) {
        int m = m0 + ty * 8 + r;
        float* co = C + (size_t)m * N + n0 + tx * 8;
#pragma unroll
        for (int c = 0; c < 8; ++c) {
            float v = acc[r][c] + bias[n0 + tx * 8 + c];
            if (ACT) v = fmaxf(v, 0.f);
            co[c] = v;
        }
    }
}

// ---------------------------------------------------------------------------
// Fused GRU1 -> streaming xp2 -> GRU2 pipeline (one persistent kernel).
// Blocks 0..127: GRU clusters (blk%8<4: GRU1 batch blk%8; else GRU2 batch-4),
//   16 WGs per cluster, wg = blk>>3. XCD-local under round-robin dispatch.
// Blocks 128..151: xp2 workers (64 out-channels each), consume hseq1 rows in
//   8-step chunks, write a 64-step xp2 ring with GRU2 back-pressure.
// Sync: sys-scope relaxed atomics; release = s_waitcnt vmcnt(0) before flag;
// acquire = poll control-dep + sched_barrier(0). No __threadfence.
// flags layout: [0..63] GRU1 WG flags, [64..127] GRU2 WG flags, [128..151] prog.
// ---------------------------------------------------------------------------
template <int MODE>
__device__ __forceinline__ void gru_cluster(
    int cb, int wg,
    const float* __restrict__ xp, const float* __restrict__ whh,
    const float* __restrict__ bhh, const float* __restrict__ skip,
    float* __restrict__ hseq, float* hb, int* flg, const int* prog,
    float* smem)
{
    int tid = threadIdx.x;
    int ch0 = wg * 32;
    int rg = tid >> 4;              // 0..23 (4 gate-rows each)
    int p = tid & 15;               // 32-wide k chunk
    float* h_lds = smem;            // 16*36 = 576 (chunk-padded)
    float* gh_lds = smem + 576;     // 96

    // resident weights: rows lr = rg*4+j -> R = (lr>>5)*512 + ch0 + (lr&31)
    float w[128];
#pragma unroll
    for (int j = 0; j < 4; ++j) {
        int lr = rg * 4 + j;
        int R = (lr >> 5) * HID + ch0 + (lr & 31);
        const float* src = whh + (size_t)R * HID + p * 32;
#pragma unroll
        for (int q = 0; q < 8; ++q) {
            float4 v = *(const float4*)&src[q * 4];
            w[j * 32 + q * 4 + 0] = v.x; w[j * 32 + q * 4 + 1] = v.y;
            w[j * 32 + q * 4 + 2] = v.z; w[j * 32 + q * 4 + 3] = v.w;
        }
    }
    float bR = 0.f, bZ = 0.f, bN = 0.f;
    if (tid < 32) {
        bR = bhh[ch0 + tid];
        bZ = bhh[HID + ch0 + tid];
        bN = bhh[2 * HID + ch0 + tid];
    }

    const size_t brow = (size_t)cb * T_LEN;
    int spin_budget = 1 << 22;      // lifetime anti-hang budget

    for (int t = 0; t < T_LEN; ++t) {
        float xr = 0.f, xz = 0.f, xn = 0.f, skv = 0.f;
        if (MODE == 1 && tid < 32) {
            // xp1/skip precomputed: plain cached prefetch before the poll
            const float* xpt = xp + (brow + t) * 1536;
            xr = xpt[ch0 + tid];
            xz = xpt[HID + ch0 + tid];
            xn = xpt[2 * HID + ch0 + tid];
            skv = skip[(brow + t) * HID + ch0 + tid];
        }
        if (MODE == 2 && tid < 64) {
            // combined poll: own h flags >= t AND xp2 progress >= t+1
            while (true) {
                int v;
                if (tid < 16)      v = __hip_atomic_load(&flg[tid], __ATOMIC_RELAXED, SCOPE_SYS);
                else if (tid < 16 + NWRK)
                                   v = __hip_atomic_load(&prog[tid - 16], __ATOMIC_RELAXED, SCOPE_SYS) - 1;
                else               v = t;
                if (__all(v >= t)) break;
                if (--spin_budget < 0) break;
            }
            __builtin_amdgcn_sched_barrier(0);
            if (tid < 32) {
                // xp row t from ring slot (sys: written by workers this kernel)
                const float* xpt = xp + ((size_t)(t & (RING - 1)) * BATCH + cb) * 1536;
                xr = __hip_atomic_load(&xpt[ch0 + tid], __ATOMIC_RELAXED, SCOPE_SYS);
                xz = __hip_atomic_load(&xpt[HID + ch0 + tid], __ATOMIC_RELAXED, SCOPE_SYS);
                xn = __hip_atomic_load(&xpt[2 * HID + ch0 + tid], __ATOMIC_RELAXED, SCOPE_SYS);
                // skip = h1 row t (sys: written by GRU1 this kernel)
                skv = __hip_atomic_load(&skip[(brow + t) * HID + ch0 + tid], __ATOMIC_RELAXED, SCOPE_SYS);
            }
        }

        if (t == 0) {
            h_lds[tid] = 0.f;
            if (tid < 192) h_lds[384 + tid] = 0.f;
        } else if (tid < 64) {
            if (MODE == 1) {
                while (true) {
                    int v = (tid < 16)
                        ? __hip_atomic_load(&flg[tid], __ATOMIC_RELAXED, SCOPE_SYS)
                        : t;
                    if (__all(v >= t)) break;
                    if (--spin_budget < 0) break;
                }
                __builtin_amdgcn_sched_barrier(0);
            }
            // coalesced sys-scope pull of h (8 x 64-lane contiguous loads)
            const float* hc = hb + (t & 1) * HID;
            float hv[8];
#pragma unroll
            for (int j = 0; j < 8; ++j)
                hv[j] = __hip_atomic_load(&hc[tid + 64 * j], __ATOMIC_RELAXED, SCOPE_SYS);
#pragma unroll
            for (int j = 0; j < 8; ++j) {
                int i = tid + 64 * j;
                h_lds[(i >> 5) * 36 + (i & 31)] = hv[j];
            }
        }
        __syncthreads();   // barrier 1: h_lds ready

        // dot: 4 gate-rows x 32-wide chunk, h from LDS
        float a0 = 0.f, a1 = 0.f, a2 = 0.f, a3 = 0.f;
#pragma unroll
        for (int q = 0; q < 8; ++q) {
            float4 hv4 = *(const float4*)&h_lds[p * 36 + q * 4];
            float hh[4] = {hv4.x, hv4.y, hv4.z, hv4.w};
#pragma unroll
            for (int e = 0; e < 4; ++e) {
                int i = q * 4 + e;
                a0 = fmaf(w[i],      hh[e], a0);
                a1 = fmaf(w[32 + i], hh[e], a1);
                a2 = fmaf(w[64 + i], hh[e], a2);
                a3 = fmaf(w[96 + i], hh[e], a3);
            }
        }
        a0 += __shfl_xor(a0, 1); a0 += __shfl_xor(a0, 2); a0 += __shfl_xor(a0, 4); a0 += __shfl_xor(a0, 8);
        a1 += __shfl_xor(a1, 1); a1 += __shfl_xor(a1, 2); a1 += __shfl_xor(a1, 4); a1 += __shfl_xor(a1, 8);
        a2 += __shfl_xor(a2, 1); a2 += __shfl_xor(a2, 2); a2 += __shfl_xor(a2, 4); a2 += __shfl_xor(a2, 8);
        a3 += __shfl_xor(a3, 1); a3 += __shfl_xor(a3, 2); a3 += __shfl_xor(a3, 4); a3 += __shfl_xor(a3, 8);
        if (p == 0) {
            gh_lds[rg * 4 + 0] = a0;
            gh_lds[rg * 4 + 1] = a1;
            gh_lds[rg * 4 + 2] = a2;
            gh_lds[rg * 4 + 3] = a3;
        }
        __syncthreads();   // barrier 2: gh_lds complete

        if (tid < 64) {    // wave 0: combine + publish
            if (tid < 32) {
                float hr = gh_lds[tid], hz = gh_lds[32 + tid], hn = gh_lds[64 + tid];
                float rr = __fdividef(1.f, 1.f + __expf(-(xr + hr + bR)));
                float zz = __fdividef(1.f, 1.f + __expf(-(xz + hz + bZ)));
                float ax = xn + rr * (hn + bN);
                float e2 = __expf(2.f * ax);
                float nn = 1.f - __fdividef(2.f, e2 + 1.f);   // tanh(ax)
                float hprev = h_lds[wg * 36 + tid];
                float hnew = (1.f - zz) * nn + zz * hprev;
                float* hnx = hb + ((t + 1) & 1) * HID;
                __hip_atomic_store(&hnx[ch0 + tid], hnew, __ATOMIC_RELAXED, SCOPE_SYS);
                float ov = hnew + skv;
                if (MODE == 1)   // consumed in-kernel by workers/GRU2 -> sys
                    __hip_atomic_store(&hseq[(brow + t) * HID + ch0 + tid], ov, __ATOMIC_RELAXED, SCOPE_SYS);
                else
                    hseq[(brow + t) * HID + ch0 + tid] = ov;
            }
            asm volatile("s_waitcnt vmcnt(0)" ::: "memory");   // release
            if (tid == 0)
                __hip_atomic_store(&flg[wg], t + 1, __ATOMIC_RELAXED, SCOPE_SYS);
        }
    }
}

__global__ __launch_bounds__(384, 2)
void k_mega(const float* __restrict__ xp1, const float* __restrict__ whh1,
            const float* __restrict__ bhh1, const float* __restrict__ h0,
            float* __restrict__ hseq1,
            const float* __restrict__ r2_wih, const float* __restrict__ r2_bih,
            const float* __restrict__ auxt, float* __restrict__ xp2r,
            const float* __restrict__ whh2, const float* __restrict__ bhh2,
            float* __restrict__ hseq2,
            float* hbuf, int* flags)
{
    __shared__ float smem[4 * 552];   // worker: hx[4][552]; gru: 576+96
    int blk = blockIdx.x;
    if (blk < 128) {
        int x8 = blk & 7;
        int wg = blk >> 3;
        if (x8 < 4)
            gru_cluster<1>(x8, wg, xp1, whh1, bhh1, h0, hseq1,
                           hbuf + x8 * 2 * HID, flags + x8 * 16, nullptr, smem);
        else
            gru_cluster<2>(x8 - 4, wg, xp2r, whh2, bhh2, hseq1, hseq2,
                           hbuf + (4 + (x8 - 4)) * 2 * HID,
                           flags + 64 + (x8 - 4) * 16, flags + 128, smem);
        return;
    }

    // ---------------- xp2 streaming workers ----------------
    int wid = blk - 128;                   // 0..23, owns out-ch [wid*64, wid*64+64)
    int tid = threadIdx.x;                 // 384; threads >=256 idle (barriers only)
    bool act = tid < 256;
    int ocg = (tid & 255) >> 3;            // 0..31
    int seg = tid & 7;                     // 0..7 (68-col segment)
    int obase = wid * 64;
    float (*hx)[552] = (float(*)[552])smem;

    float w2[2][68];
    float bz[2] = {0.f, 0.f};
    if (act) {
#pragma unroll
        for (int j = 0; j < 2; ++j) {
            int o = obase + j * 32 + ocg;
            const float* src = r2_wih + (size_t)o * 544 + seg * 68;
#pragma unroll
            for (int q = 0; q < 17; ++q) {
                float4 v = *(const float4*)&src[q * 4];
                w2[j][q * 4 + 0] = v.x; w2[j][q * 4 + 1] = v.y;
                w2[j][q * 4 + 2] = v.z; w2[j][q * 4 + 3] = v.w;
            }
            bz[j] = r2_bih[o];
        }
    }
    int* flg1 = flags;          // 64 GRU1 flags
    int* flg2 = flags + 64;     // 64 GRU2 flags (ring back-pressure)
    int* prog = flags + 128;
    int spin_budget = 1 << 22;

    for (int c0 = 0; c0 < T_LEN; c0 += 8) {
        if (tid < 64) {
            int need1 = c0 + 8;          // h1 rows [c0, c0+8) ready
            int need2 = c0 - (RING - 8); // GRU2 consumed rows we overwrite
            while (true) {
                int v1 = __hip_atomic_load(&flg1[tid], __ATOMIC_RELAXED, SCOPE_SYS);
                int v2 = (need2 > 0)
                    ? __hip_atomic_load(&flg2[tid], __ATOMIC_RELAXED, SCOPE_SYS)
                    : need2;
                if (__all(v1 >= need1 && v2 >= need2)) break;
                if (--spin_budget < 0) break;
            }
            __builtin_amdgcn_sched_barrier(0);
        }
        __syncthreads();
        for (int t = c0; t < c0 + 8; ++t) {
            if (act) {
#pragma unroll
                for (int k = 0; k < 8; ++k) {
                    int j = tid + 256 * k;           // < 2048
                    int b = j >> 9, i = j & 511;
                    hx[b][i] = __hip_atomic_load(
                        &hseq1[((size_t)b * T_LEN + t) * HID + i],
                        __ATOMIC_RELAXED, SCOPE_SYS);
                }
                if (tid < 128) {
                    int b = tid >> 5, i = tid & 31;
                    hx[b][512 + i] = auxt[((size_t)b * T_LEN + t) * CCH + 32 + i];
                }
            }
            __syncthreads();
            if (act) {
                float acc[2][4] = {{0.f,0.f,0.f,0.f},{0.f,0.f,0.f,0.f}};
                int s68 = seg * 68;
#pragma unroll
                for (int q = 0; q < 17; ++q) {
                    float4 h0v = *(const float4*)&hx[0][s68 + q * 4];
                    float4 h1v = *(const float4*)&hx[1][s68 + q * 4];
                    float4 h2v = *(const float4*)&hx[2][s68 + q * 4];
                    float4 h3v = *(const float4*)&hx[3][s68 + q * 4];
                    float hb0[4] = {h0v.x, h0v.y, h0v.z, h0v.w};
                    float hb1[4] = {h1v.x, h1v.y, h1v.z, h1v.w};
                    float hb2[4] = {h2v.x, h2v.y, h2v.z, h2v.w};
                    float hb3[4] = {h3v.x, h3v.y, h3v.z, h3v.w};
#pragma unroll
                    for (int u = 0; u < 4; ++u) {
                        float w0 = w2[0][q * 4 + u], w1 = w2[1][q * 4 + u];
                        acc[0][0] = fmaf(w0, hb0[u], acc[0][0]);
                        acc[0][1] = fmaf(w0, hb1[u], acc[0][1]);
                        acc[0][2] = fmaf(w0, hb2[u], acc[0][2]);
                        acc[0][3] = fmaf(w0, hb3[u], acc[0][3]);
                        acc[1][0] = fmaf(w1, hb0[u], acc[1][0]);
                        acc[1][1] = fmaf(w1, hb1[u], acc[1][1]);
                        acc[1][2] = fmaf(w1, hb2[u], acc[1][2]);
                        acc[1][3] = fmaf(w1, hb3[u], acc[1][3]);
                    }
                }
#pragma unroll
                for (int j = 0; j < 2; ++j)
#pragma unroll
                    for (int b = 0; b < 4; ++b) {
                        float a = acc[j][b];
                        a += __shfl_xor(a, 1); a += __shfl_xor(a, 2); a += __shfl_xor(a, 4);
                        acc[j][b] = a;
                    }
                if (seg == 0) {
#pragma unroll
                    for (int j = 0; j < 2; ++j)
#pragma unroll
                        for (int b = 0; b < 4; ++b)
                            __hip_atomic_store(
                                &xp2r[((size_t)(t & (RING - 1)) * BATCH + b) * 1536
                                      + obase + j * 32 + ocg],
                                acc[j][b] + bz[j], __ATOMIC_RELAXED, SCOPE_SYS);
                }
            }
            __syncthreads();
        }
        asm volatile("s_waitcnt vmcnt(0)" ::: "memory");   // release ring writes
        if (tid == 0)
            __hip_atomic_store(&prog[wid], c0 + 8, __ATOMIC_RELAXED, SCOPE_SYS);
    }
}

// ---------------------------------------------------------------------------
extern "C" void kernel_launch(void* const* d_in, const int* in_sizes, int n_in,
                              void* d_out, int out_size, void* d_ws, size_t ws_size,
                              hipStream_t stream) {
    (void)in_sizes; (void)n_in; (void)out_size; (void)ws_size;
    const float* x         = (const float*)d_in[0];
    const float* mels      = (const float*)d_in[1];
    const float* conv_in_w = (const float*)d_in[2];
    const float* bn0_g     = (const float*)d_in[3];
    const float* bn0_b     = (const float*)d_in[4];
    const float* res_c1    = (const float*)d_in[5];
    const float* res_c2    = (const float*)d_in[6];
    const float* res_bn1_g = (const float*)d_in[7];
    const float* res_bn1_b = (const float*)d_in[8];
    const float* res_bn2_g = (const float*)d_in[9];
    const float* res_bn2_b = (const float*)d_in[10];
    const float* conv_out_w= (const float*)d_in[11];
    const float* conv_out_b= (const float*)d_in[12];
    const float* up_w0     = (const float*)d_in[13];
    const float* up_w1     = (const float*)d_in[14];
    const float* up_w2     = (const float*)d_in[15];
    const float* I_w       = (const float*)d_in[16];
    const float* I_b       = (const float*)d_in[17];
    const float* r1_wih    = (const float*)d_in[18];
    const float* r1_whh    = (const float*)d_in[19];
    const float* r1_bih    = (const float*)d_in[20];
    const float* r1_bhh    = (const float*)d_in[21];
    const float* r2_wih    = (const float*)d_in[22];
    const float* r2_whh    = (const float*)d_in[23];
    const float* r2_bih    = (const float*)d_in[24];
    const float* r2_bhh    = (const float*)d_in[25];
    const float* fc1_w     = (const float*)d_in[26];
    const float* fc1_b     = (const float*)d_in[27];
    const float* fc2_w     = (const float*)d_in[28];
    const float* fc2_b     = (const float*)d_in[29];
    const float* fc3_w     = (const float*)d_in[30];
    const float* fc3_b     = (const float*)d_in[31];

    char* ws = (char*)d_ws;
    size_t off = 0;
    auto alloc = [&](size_t bytes) {
        char* p = ws + off;
        off += (bytes + 255) & ~(size_t)255;
        return p;
    };
    int*   flagsA = (int*)  alloc(1024);                     // flags1|flags2|prog
    float* hbuf   = (float*)alloc(8 * 2 * HID * 4);
    float* xp2r   = (float*)alloc((size_t)RING * BATCH * 1536 * 4);  // 1.6MB ring
    float* rnA    = (float*)alloc((size_t)BATCH * CCH * LRES * 4);
    float* rnB    = (float*)alloc((size_t)BATCH * CCH * LRES * 4);
    float* aux_s  = (float*)alloc((size_t)BATCH * CCH * LRES * 4);
    float* s1     = (float*)alloc((size_t)BATCH * NFEAT * 216 * 4);
    float* s2     = (float*)alloc((size_t)BATCH * NFEAT * 1728 * 4);
    float* mup    = (float*)alloc((size_t)BATCH * T_LEN * NFEAT * 4);
    float* auxt   = (float*)alloc((size_t)BATCH * T_LEN * CCH * 4);
    float* h0     = (float*)alloc((size_t)M_ROWS * HID * 4);
    float* xp     = (float*)alloc((size_t)M_ROWS * 1536 * 4);
    float* h1     = (float*)alloc((size_t)M_ROWS * HID * 4);
    float* h2     = (float*)alloc((size_t)M_ROWS * HID * 4);
    float* f1 = h0;   // h0 dead after mega kernel
    float* f2 = h1;   // h1 dead after mega kernel

    hipMemsetAsync(flagsA, 0, 1024, stream);

    // mel resnet
    k_conv_in<<<BATCH * LRES, 128, 0, stream>>>(mels, conv_in_w, bn0_g, bn0_b, rnA);
    for (int i = 0; i < 10; ++i) {
        k_ein<0><<<BATCH * LRES, 128, 0, stream>>>(rnA, res_c1 + (size_t)i * CCH * CCH,
            res_bn1_g + i * CCH, res_bn1_b + i * CCH, nullptr, rnB);
        k_ein<1><<<BATCH * LRES, 128, 0, stream>>>(rnB, res_c2 + (size_t)i * CCH * CCH,
            res_bn2_g + i * CCH, res_bn2_b + i * CCH, rnA, rnA);
    }
    k_ein<2><<<BATCH * LRES, 128, 0, stream>>>(rnA, conv_out_w, nullptr, conv_out_b, nullptr, aux_s);
    k_auxrep<<<(BATCH * T_LEN * CCH) / 256, 256, 0, stream>>>(aux_s, auxt);

    // upsample
    k_up1<<<(BATCH * NFEAT * 216) / 256, 256, 0, stream>>>(mels, up_w0, s1);
    k_up2<<<(BATCH * NFEAT * 1728) / 256, 256, 0, stream>>>(s1, up_w1, s2);
    k_up3<<<(BATCH * T_LEN * NFEAT) / 256, 256, 0, stream>>>(s2, up_w2, mup);

    // h0 = concat(x, m_up, a1) @ I_w^T + I_b
    gemm_f32<0><<<dim3(512 / 128, M_ROWS / 128), 256, 0, stream>>>(
        x, 1, 1, mup, NFEAT, NFEAT, auxt, CCH, 32, I_w, I_b, h0, 512, 113);
    // xp1 = h0 @ r1_wih^T + r1_bih
    gemm_f32<0><<<dim3(1536 / 128, M_ROWS / 128), 256, 0, stream>>>(
        h0, HID, HID, nullptr, 0, 0, nullptr, 0, 0, r1_wih, r1_bih, xp, 1536, 512);

    // fused GRU1 -> xp2 workers -> GRU2
    k_mega<<<152, 384, 0, stream>>>(xp, r1_whh, r1_bhh, h0, h1,
                                    r2_wih, r2_bih, auxt, xp2r,
                                    r2_whh, r2_bhh, h2, hbuf, flagsA);

    // fc chain
    gemm_f32<1><<<dim3(512 / 128, M_ROWS / 128), 256, 0, stream>>>(
        h2, HID, HID, auxt + 64, CCH, 32, nullptr, 0, 0, fc1_w, fc1_b, f1, 512, 544);
    gemm_f32<1><<<dim3(512 / 128, M_ROWS / 128), 256, 0, stream>>>(
        f1, HID, HID, auxt + 96, CCH, 32, nullptr, 0, 0, fc2_w, fc2_b, f2, 512, 544);
    gemm_f32<0><<<dim3(1024 / 128, M_ROWS / 128), 256, 0, stream>>>(
        f2, HID, HID, nullptr, 0, 0, nullptr, 0, 0, fc3_w, fc3_b, (float*)d_out, 1024, 512);
}